// Round 2
// baseline (302.132 us; speedup 1.0000x reference)
//
#include <hip/hip_runtime.h>
#include <math.h>

namespace {
constexpr int COARSE = 32;
constexpr int NATOMS = 16;
constexpr int NPT    = 767;   // N_INT - 1
constexpr int NRAYS  = 256;
constexpr double VOXEL_D = 1.3 * 2.0 / 32.0 / 4.0;
constexpr float  VOXEL_F = (float)VOXEL_D;
constexpr float  STEP_F  = (float)(VOXEL_D / 2.0);
constexpr float  RAD     = 1.3f;
}

__global__ __launch_bounds__(1024, 1)
void shdict_render(const float* __restrict__ rays_o,
                   const float* __restrict__ rays_d,
                   const float* __restrict__ grid,
                   const float* __restrict__ atoms,
                   float* __restrict__ out)
{
  const int ray = blockIdx.x;
  const int tid = threadIdx.x;

  __shared__ float s_alpha[NPT];
  __shared__ float s_rgb[NPT][3];

  const float ox = rays_o[ray*3+0], oy = rays_o[ray*3+1], oz = rays_o[ray*3+2];
  const float dx = rays_d[ray*3+0], dy = rays_d[ray*3+1], dz = rays_d[ray*3+2];

  const float m0 = fminf((RAD - ox)/dx, (-RAD - ox)/dx);
  const float m1 = fminf((RAD - oy)/dy, (-RAD - oy)/dy);
  const float m2 = fminf((RAD - oz)/dz, (-RAD - oz)/dz);
  const float start = fmaxf(fmaxf(m0, m1), m2);

  const float dnorm = sqrtf(dx*dx + dy*dy + dz*dz);
  const float inx = dx/dnorm, iny = dy/dnorm, inz = dz/dnorm;
  float sh[9];
  sh[0] = 0.28209479177387814f;
  sh[1] = -0.4886025119029199f*iny;
  sh[2] =  0.4886025119029199f*inz;
  sh[3] = -0.4886025119029199f*inx;
  sh[4] =  1.0925484305920792f*inx*iny;
  sh[5] = -1.0925484305920792f*iny*inz;
  sh[6] =  0.31539156525252005f*(2.0f*inz*inz - inx*inx - iny*iny);
  sh[7] = -1.0925484305920792f*inx*inz;
  sh[8] =  0.5462742152960396f*(inx*inx - iny*iny);

  float* alpha_out = out + NRAYS*3;

  const int half = tid & 1;          // which 4 corners this thread owns
  const int pidx = tid >> 1;         // point index within the half-block

  for (int h = 0; h < 2; ++h) {
    const int j = h*512 + pidx;
    if (j < NPT) {
      const float t  = start + (float)j * STEP_F;
      const float px = ox + t*dx;
      const float py = oy + t*dy;
      const float pz = oz + t*dz;
      const bool inb = (px > -RAD) && (px < RAD) && (py > -RAD) && (py < RAD)
                    && (pz > -RAD) && (pz < RAD);
      float a = 0.0f, r0 = 0.5f, r1 = 0.5f, r2 = 0.5f;
      if (inb) {
        const float ux = (px + RAD) / VOXEL_F;
        const float uy = (py + RAD) / VOXEL_F;
        const float uz = (pz + RAD) / VOXEL_F;
        float4 acc4[7];
        #pragma unroll
        for (int q = 0; q < 7; ++q) acc4[q] = make_float4(0.f,0.f,0.f,0.f);

        #pragma unroll
        for (int cc = 0; cc < 4; ++cc) {
          const int corner = half*4 + cc;
          const float sx = (corner & 4) ? 0.5f : -0.5f;
          const float sy = (corner & 2) ? 0.5f : -0.5f;
          const float sz = (corner & 1) ? 0.5f : -0.5f;
          const float pfx = fminf(fmaxf(floorf(ux + sx), 0.0f), 127.0f);
          const float pfy = fminf(fmaxf(floorf(uy + sy), 0.0f), 127.0f);
          const float pfz = fminf(fmaxf(floorf(uz + sz), 0.0f), 127.0f);
          const float fx = fabsf(ux - (pfx + 0.5f));
          const float fy = fabsf(uy - (pfy + 0.5f));
          const float fz = fabsf(uz - (pfz + 0.5f));
          const float w = (1.0f-fx)*(1.0f-fy)*(1.0f-fz);
          const int ix = (int)pfx, iy = (int)pfy, iz = (int)pfz;
          const int cell = ((ix >> 2)*COARSE + (iy >> 2))*COARSE + (iz >> 2);
          const int fine = ((ix & 3)*4 + (iy & 3))*4 + (iz & 3);
          const float4* cv = (const float4*)(grid + (long)cell*448);
          const float4* fv = (const float4*)(atoms + (long)fine*448);
          float4 res[7];
          #pragma unroll
          for (int q = 0; q < 7; ++q) res[q] = make_float4(0.f,0.f,0.f,0.f);
          for (int aa = 0; aa < NATOMS; ++aa) {
            #pragma unroll
            for (int q = 0; q < 7; ++q) {
              const float4 c = cv[aa*7 + q];
              const float4 f = fv[aa*7 + q];
              res[q].x += c.x*f.x;
              res[q].y += c.y*f.y;
              res[q].z += c.z*f.z;
              res[q].w += c.w*f.w;
            }
          }
          #pragma unroll
          for (int q = 0; q < 7; ++q) {
            acc4[q].x += w*res[q].x;
            acc4[q].y += w*res[q].y;
            acc4[q].z += w*res[q].z;
            acc4[q].w += w*res[q].w;
          }
        }

        // Combine the two 4-corner halves across the lane pair.
        // Both lanes of a pair are active together (same j, same inb),
        // so the shuffle always reads an active partner lane.
        #pragma unroll
        for (int q = 0; q < 7; ++q) {
          acc4[q].x += __shfl_xor(acc4[q].x, 1, 64);
          acc4[q].y += __shfl_xor(acc4[q].y, 1, 64);
          acc4[q].z += __shfl_xor(acc4[q].z, 1, 64);
          acc4[q].w += __shfl_xor(acc4[q].w, 1, 64);
        }

        const float* data = (const float*)acc4;
        const float sigma = fmaxf(data[27], 0.0f);
        const float dist  = STEP_F * dnorm;
        a = 1.0f - expf(-sigma * dist);
        float p0 = 0.f, p1 = 0.f, p2 = 0.f;
        #pragma unroll
        for (int k = 0; k < 9; ++k) {
          p0 += sh[k]*data[k];
          p1 += sh[k]*data[9+k];
          p2 += sh[k]*data[18+k];
        }
        r0 = 1.0f/(1.0f + expf(-p0));
        r1 = 1.0f/(1.0f + expf(-p1));
        r2 = 1.0f/(1.0f + expf(-p2));
      }
      if (half == 0) {
        s_alpha[j]  = a;
        s_rgb[j][0] = r0; s_rgb[j][1] = r1; s_rgb[j][2] = r2;
        alpha_out[ray*NPT + j] = a;
      }
    }
  }
  __syncthreads();

  // Phase 2: transmittance scan + outputs, one wave per ray (wave 0 of block)
  if (tid < 64) {
    const int lane = tid;
    float carry = 1.0f;
    float acc = 0.f, dep = 0.f, c0 = 0.f, c1 = 0.f, c2 = 0.f;
    for (int chunk = 0; chunk < 12; ++chunk) {
      const int j = chunk*64 + lane;
      const float a = (j < NPT) ? s_alpha[j] : 0.0f;
      const float v = 1.0f - a + 1e-10f;
      float s = v;
      #pragma unroll
      for (int off = 1; off < 64; off <<= 1) {
        const float o = __shfl_up(s, off, 64);
        if (lane >= off) s *= o;
      }
      float excl = __shfl_up(s, 1, 64);
      if (lane == 0) excl = 1.0f;
      const float T = carry * excl;
      if (j < NPT) {
        const float al = a * T;
        acc += al;
        const float t = start + (float)j * STEP_F;
        dep += al * t;
        c0 += al * s_rgb[j][0];
        c1 += al * s_rgb[j][1];
        c2 += al * s_rgb[j][2];
      }
      carry *= __shfl(s, 63, 64);
    }
    #pragma unroll
    for (int off = 32; off >= 1; off >>= 1) {
      acc += __shfl_down(acc, off, 64);
      dep += __shfl_down(dep, off, 64);
      c0  += __shfl_down(c0,  off, 64);
      c1  += __shfl_down(c1,  off, 64);
      c2  += __shfl_down(c2,  off, 64);
    }
    if (lane == 0) {
      const float bg = 1.0f - acc;
      out[ray*3+0] = c0 + bg;
      out[ray*3+1] = c1 + bg;
      out[ray*3+2] = c2 + bg;
      out[NRAYS*3 + NRAYS*NPT + ray] = dep;
      if (ray == 0) out[NRAYS*3 + NRAYS*NPT + NRAYS] = 0.0f;
    }
  }
}

extern "C" void kernel_launch(void* const* d_in, const int* in_sizes, int n_in,
                              void* d_out, int out_size, void* d_ws, size_t ws_size,
                              hipStream_t stream) {
  const float* rays_o = (const float*)d_in[0];
  const float* rays_d = (const float*)d_in[1];
  const float* grid   = (const float*)d_in[2];
  const float* atoms  = (const float*)d_in[3];
  (void)in_sizes; (void)n_in; (void)out_size; (void)d_ws; (void)ws_size;
  hipLaunchKernelGGL(shdict_render, dim3(NRAYS), dim3(1024), 0, stream,
                     rays_o, rays_d, grid, atoms, (float*)d_out);
}

// Round 3
// 275.917 us; speedup vs baseline: 1.0950x; 1.0950x over previous
//
#include <hip/hip_runtime.h>
#include <math.h>

namespace {
constexpr int COARSE = 32;
constexpr int NATOMS = 16;
constexpr int NPT    = 767;   // N_INT - 1
constexpr int NRAYS  = 256;
constexpr int NPTS_TOTAL = NRAYS * NPT;  // 196352
constexpr double VOXEL_D = 1.3 * 2.0 / 32.0 / 4.0;
constexpr float  VOXEL_F = (float)VOXEL_D;
constexpr float  STEP_F  = (float)(VOXEL_D / 2.0);
constexpr float  RAD     = 1.3f;
}

// ---------------------------------------------------------------------------
// Kernel A: per-point gather + shading. One thread per sample point.
// Writes alpha into out (it is an output) and rgb_s into 3 planes of ws.
// ---------------------------------------------------------------------------
__global__ __launch_bounds__(256)
void shdict_gather(const float* __restrict__ rays_o,
                   const float* __restrict__ rays_d,
                   const float* __restrict__ grid,
                   const float* __restrict__ atoms,
                   float* __restrict__ out,
                   float* __restrict__ ws)
{
  const int p = blockIdx.x * 256 + threadIdx.x;
  if (p >= NPTS_TOTAL) return;
  const int ray = p / NPT;
  const int j   = p - ray * NPT;

  const float ox = rays_o[ray*3+0], oy = rays_o[ray*3+1], oz = rays_o[ray*3+2];
  const float dx = rays_d[ray*3+0], dy = rays_d[ray*3+1], dz = rays_d[ray*3+2];

  const float m0 = fminf((RAD - ox)/dx, (-RAD - ox)/dx);
  const float m1 = fminf((RAD - oy)/dy, (-RAD - oy)/dy);
  const float m2 = fminf((RAD - oz)/dz, (-RAD - oz)/dz);
  const float start = fmaxf(fmaxf(m0, m1), m2);

  const float dnorm = sqrtf(dx*dx + dy*dy + dz*dz);

  const float t  = start + (float)j * STEP_F;
  const float px = ox + t*dx;
  const float py = oy + t*dy;
  const float pz = oz + t*dz;
  const bool inb = (px > -RAD) && (px < RAD) && (py > -RAD) && (py < RAD)
                && (pz > -RAD) && (pz < RAD);
  float a = 0.0f, r0 = 0.5f, r1 = 0.5f, r2 = 0.5f;
  if (inb) {
    const float inx = dx/dnorm, iny = dy/dnorm, inz = dz/dnorm;
    float sh[9];
    sh[0] = 0.28209479177387814f;
    sh[1] = -0.4886025119029199f*iny;
    sh[2] =  0.4886025119029199f*inz;
    sh[3] = -0.4886025119029199f*inx;
    sh[4] =  1.0925484305920792f*inx*iny;
    sh[5] = -1.0925484305920792f*iny*inz;
    sh[6] =  0.31539156525252005f*(2.0f*inz*inz - inx*inx - iny*iny);
    sh[7] = -1.0925484305920792f*inx*inz;
    sh[8] =  0.5462742152960396f*(inx*inx - iny*iny);

    const float ux = (px + RAD) / VOXEL_F;
    const float uy = (py + RAD) / VOXEL_F;
    const float uz = (pz + RAD) / VOXEL_F;
    float4 acc4[7];
    #pragma unroll
    for (int q = 0; q < 7; ++q) acc4[q] = make_float4(0.f,0.f,0.f,0.f);

    for (int corner = 0; corner < 8; ++corner) {
      const float sx = (corner & 4) ? 0.5f : -0.5f;
      const float sy = (corner & 2) ? 0.5f : -0.5f;
      const float sz = (corner & 1) ? 0.5f : -0.5f;
      const float pfx = fminf(fmaxf(floorf(ux + sx), 0.0f), 127.0f);
      const float pfy = fminf(fmaxf(floorf(uy + sy), 0.0f), 127.0f);
      const float pfz = fminf(fmaxf(floorf(uz + sz), 0.0f), 127.0f);
      const float fx = fabsf(ux - (pfx + 0.5f));
      const float fy = fabsf(uy - (pfy + 0.5f));
      const float fz = fabsf(uz - (pfz + 0.5f));
      const float w = (1.0f-fx)*(1.0f-fy)*(1.0f-fz);
      const int ix = (int)pfx, iy = (int)pfy, iz = (int)pfz;
      const int cell = ((ix >> 2)*COARSE + (iy >> 2))*COARSE + (iz >> 2);
      const int fine = ((ix & 3)*4 + (iy & 3))*4 + (iz & 3);
      const float4* cv = (const float4*)(grid + (long)cell*448);
      const float4* fv = (const float4*)(atoms + (long)fine*448);
      float4 res[7];
      #pragma unroll
      for (int q = 0; q < 7; ++q) res[q] = make_float4(0.f,0.f,0.f,0.f);
      for (int aa = 0; aa < NATOMS; ++aa) {
        #pragma unroll
        for (int q = 0; q < 7; ++q) {
          const float4 c = cv[aa*7 + q];
          const float4 f = fv[aa*7 + q];
          res[q].x += c.x*f.x;
          res[q].y += c.y*f.y;
          res[q].z += c.z*f.z;
          res[q].w += c.w*f.w;
        }
      }
      #pragma unroll
      for (int q = 0; q < 7; ++q) {
        acc4[q].x += w*res[q].x;
        acc4[q].y += w*res[q].y;
        acc4[q].z += w*res[q].z;
        acc4[q].w += w*res[q].w;
      }
    }
    const float* data = (const float*)acc4;
    const float sigma = fmaxf(data[27], 0.0f);
    const float dist  = STEP_F * dnorm;
    a = 1.0f - expf(-sigma * dist);
    float p0 = 0.f, p1 = 0.f, p2 = 0.f;
    #pragma unroll
    for (int k = 0; k < 9; ++k) {
      p0 += sh[k]*data[k];
      p1 += sh[k]*data[9+k];
      p2 += sh[k]*data[18+k];
    }
    r0 = 1.0f/(1.0f + expf(-p0));
    r1 = 1.0f/(1.0f + expf(-p1));
    r2 = 1.0f/(1.0f + expf(-p2));
  }
  out[NRAYS*3 + p] = a;           // alpha output plane
  ws[0*NPTS_TOTAL + p] = r0;
  ws[1*NPTS_TOTAL + p] = r1;
  ws[2*NPTS_TOTAL + p] = r2;
}

// ---------------------------------------------------------------------------
// Kernel B: transmittance scan + reductions. One wave per ray.
// ---------------------------------------------------------------------------
__global__ __launch_bounds__(256)
void shdict_scan(const float* __restrict__ rays_o,
                 const float* __restrict__ rays_d,
                 const float* __restrict__ ws,
                 float* __restrict__ out)
{
  const int wave = threadIdx.x >> 6;
  const int lane = threadIdx.x & 63;
  const int ray  = blockIdx.x * 4 + wave;
  if (ray >= NRAYS) return;

  const float ox = rays_o[ray*3+0], oy = rays_o[ray*3+1], oz = rays_o[ray*3+2];
  const float dx = rays_d[ray*3+0], dy = rays_d[ray*3+1], dz = rays_d[ray*3+2];
  const float m0 = fminf((RAD - ox)/dx, (-RAD - ox)/dx);
  const float m1 = fminf((RAD - oy)/dy, (-RAD - oy)/dy);
  const float m2 = fminf((RAD - oz)/dz, (-RAD - oz)/dz);
  const float start = fmaxf(fmaxf(m0, m1), m2);

  const float* alpha = out + NRAYS*3 + ray*NPT;

  float carry = 1.0f;
  float acc = 0.f, dep = 0.f, c0 = 0.f, c1 = 0.f, c2 = 0.f;
  for (int chunk = 0; chunk < 12; ++chunk) {
    const int j = chunk*64 + lane;
    const float a = (j < NPT) ? alpha[j] : 0.0f;
    const float v = 1.0f - a + 1e-10f;
    float s = v;
    #pragma unroll
    for (int off = 1; off < 64; off <<= 1) {
      const float o = __shfl_up(s, off, 64);
      if (lane >= off) s *= o;
    }
    float excl = __shfl_up(s, 1, 64);
    if (lane == 0) excl = 1.0f;
    const float T = carry * excl;
    if (j < NPT) {
      const int p = ray*NPT + j;
      const float al = a * T;
      acc += al;
      const float t = start + (float)j * STEP_F;
      dep += al * t;
      c0 += al * ws[0*NPTS_TOTAL + p];
      c1 += al * ws[1*NPTS_TOTAL + p];
      c2 += al * ws[2*NPTS_TOTAL + p];
    }
    carry *= __shfl(s, 63, 64);
  }
  #pragma unroll
  for (int off = 32; off >= 1; off >>= 1) {
    acc += __shfl_down(acc, off, 64);
    dep += __shfl_down(dep, off, 64);
    c0  += __shfl_down(c0,  off, 64);
    c1  += __shfl_down(c1,  off, 64);
    c2  += __shfl_down(c2,  off, 64);
  }
  if (lane == 0) {
    const float bg = 1.0f - acc;
    out[ray*3+0] = c0 + bg;
    out[ray*3+1] = c1 + bg;
    out[ray*3+2] = c2 + bg;
    out[NRAYS*3 + NRAYS*NPT + ray] = dep;
    if (ray == 0) out[NRAYS*3 + NRAYS*NPT + NRAYS] = 0.0f;
  }
}

// ---------------------------------------------------------------------------
// Fallback: the round-1 fused kernel (used only if ws is too small).
// ---------------------------------------------------------------------------
__global__ __launch_bounds__(256)
void shdict_render_fused(const float* __restrict__ rays_o,
                         const float* __restrict__ rays_d,
                         const float* __restrict__ grid,
                         const float* __restrict__ atoms,
                         float* __restrict__ out)
{
  const int ray = blockIdx.x;
  const int tid = threadIdx.x;

  __shared__ float s_alpha[NPT];
  __shared__ float s_rgb[NPT][3];

  const float ox = rays_o[ray*3+0], oy = rays_o[ray*3+1], oz = rays_o[ray*3+2];
  const float dx = rays_d[ray*3+0], dy = rays_d[ray*3+1], dz = rays_d[ray*3+2];

  const float m0 = fminf((RAD - ox)/dx, (-RAD - ox)/dx);
  const float m1 = fminf((RAD - oy)/dy, (-RAD - oy)/dy);
  const float m2 = fminf((RAD - oz)/dz, (-RAD - oz)/dz);
  const float start = fmaxf(fmaxf(m0, m1), m2);

  const float dnorm = sqrtf(dx*dx + dy*dy + dz*dz);
  const float inx = dx/dnorm, iny = dy/dnorm, inz = dz/dnorm;
  float sh[9];
  sh[0] = 0.28209479177387814f;
  sh[1] = -0.4886025119029199f*iny;
  sh[2] =  0.4886025119029199f*inz;
  sh[3] = -0.4886025119029199f*inx;
  sh[4] =  1.0925484305920792f*inx*iny;
  sh[5] = -1.0925484305920792f*iny*inz;
  sh[6] =  0.31539156525252005f*(2.0f*inz*inz - inx*inx - iny*iny);
  sh[7] = -1.0925484305920792f*inx*inz;
  sh[8] =  0.5462742152960396f*(inx*inx - iny*iny);

  float* alpha_out = out + NRAYS*3;

  for (int j = tid; j < NPT; j += 256) {
    const float t  = start + (float)j * STEP_F;
    const float px = ox + t*dx;
    const float py = oy + t*dy;
    const float pz = oz + t*dz;
    const bool inb = (px > -RAD) && (px < RAD) && (py > -RAD) && (py < RAD)
                  && (pz > -RAD) && (pz < RAD);
    float a = 0.0f, r0 = 0.5f, r1 = 0.5f, r2 = 0.5f;
    if (inb) {
      const float ux = (px + RAD) / VOXEL_F;
      const float uy = (py + RAD) / VOXEL_F;
      const float uz = (pz + RAD) / VOXEL_F;
      float4 acc4[7];
      #pragma unroll
      for (int q = 0; q < 7; ++q) acc4[q] = make_float4(0.f,0.f,0.f,0.f);
      for (int corner = 0; corner < 8; ++corner) {
        const float sx = (corner & 4) ? 0.5f : -0.5f;
        const float sy = (corner & 2) ? 0.5f : -0.5f;
        const float sz = (corner & 1) ? 0.5f : -0.5f;
        const float pfx = fminf(fmaxf(floorf(ux + sx), 0.0f), 127.0f);
        const float pfy = fminf(fmaxf(floorf(uy + sy), 0.0f), 127.0f);
        const float pfz = fminf(fmaxf(floorf(uz + sz), 0.0f), 127.0f);
        const float fx = fabsf(ux - (pfx + 0.5f));
        const float fy = fabsf(uy - (pfy + 0.5f));
        const float fz = fabsf(uz - (pfz + 0.5f));
        const float w = (1.0f-fx)*(1.0f-fy)*(1.0f-fz);
        const int ix = (int)pfx, iy = (int)pfy, iz = (int)pfz;
        const int cell = ((ix >> 2)*COARSE + (iy >> 2))*COARSE + (iz >> 2);
        const int fine = ((ix & 3)*4 + (iy & 3))*4 + (iz & 3);
        const float4* cv = (const float4*)(grid + (long)cell*448);
        const float4* fv = (const float4*)(atoms + (long)fine*448);
        float4 res[7];
        #pragma unroll
        for (int q = 0; q < 7; ++q) res[q] = make_float4(0.f,0.f,0.f,0.f);
        for (int aa = 0; aa < NATOMS; ++aa) {
          #pragma unroll
          for (int q = 0; q < 7; ++q) {
            const float4 c = cv[aa*7 + q];
            const float4 f = fv[aa*7 + q];
            res[q].x += c.x*f.x;
            res[q].y += c.y*f.y;
            res[q].z += c.z*f.z;
            res[q].w += c.w*f.w;
          }
        }
        #pragma unroll
        for (int q = 0; q < 7; ++q) {
          acc4[q].x += w*res[q].x;
          acc4[q].y += w*res[q].y;
          acc4[q].z += w*res[q].z;
          acc4[q].w += w*res[q].w;
        }
      }
      const float* data = (const float*)acc4;
      const float sigma = fmaxf(data[27], 0.0f);
      a = 1.0f - expf(-sigma * (STEP_F * dnorm));
      float p0 = 0.f, p1 = 0.f, p2 = 0.f;
      #pragma unroll
      for (int k = 0; k < 9; ++k) {
        p0 += sh[k]*data[k];
        p1 += sh[k]*data[9+k];
        p2 += sh[k]*data[18+k];
      }
      r0 = 1.0f/(1.0f + expf(-p0));
      r1 = 1.0f/(1.0f + expf(-p1));
      r2 = 1.0f/(1.0f + expf(-p2));
    }
    s_alpha[j]  = a;
    s_rgb[j][0] = r0; s_rgb[j][1] = r1; s_rgb[j][2] = r2;
    alpha_out[ray*NPT + j] = a;
  }
  __syncthreads();

  if (tid < 64) {
    const int lane = tid;
    float carry = 1.0f;
    float acc = 0.f, dep = 0.f, c0 = 0.f, c1 = 0.f, c2 = 0.f;
    for (int chunk = 0; chunk < 12; ++chunk) {
      const int j = chunk*64 + lane;
      const float a = (j < NPT) ? s_alpha[j] : 0.0f;
      const float v = 1.0f - a + 1e-10f;
      float s = v;
      #pragma unroll
      for (int off = 1; off < 64; off <<= 1) {
        const float o = __shfl_up(s, off, 64);
        if (lane >= off) s *= o;
      }
      float excl = __shfl_up(s, 1, 64);
      if (lane == 0) excl = 1.0f;
      const float T = carry * excl;
      if (j < NPT) {
        const float al = a * T;
        acc += al;
        dep += al * (start + (float)j * STEP_F);
        c0 += al * s_rgb[j][0];
        c1 += al * s_rgb[j][1];
        c2 += al * s_rgb[j][2];
      }
      carry *= __shfl(s, 63, 64);
    }
    #pragma unroll
    for (int off = 32; off >= 1; off >>= 1) {
      acc += __shfl_down(acc, off, 64);
      dep += __shfl_down(dep, off, 64);
      c0  += __shfl_down(c0,  off, 64);
      c1  += __shfl_down(c1,  off, 64);
      c2  += __shfl_down(c2,  off, 64);
    }
    if (lane == 0) {
      const float bg = 1.0f - acc;
      out[ray*3+0] = c0 + bg;
      out[ray*3+1] = c1 + bg;
      out[ray*3+2] = c2 + bg;
      out[NRAYS*3 + NRAYS*NPT + ray] = dep;
      if (ray == 0) out[NRAYS*3 + NRAYS*NPT + NRAYS] = 0.0f;
    }
  }
}

extern "C" void kernel_launch(void* const* d_in, const int* in_sizes, int n_in,
                              void* d_out, int out_size, void* d_ws, size_t ws_size,
                              hipStream_t stream) {
  const float* rays_o = (const float*)d_in[0];
  const float* rays_d = (const float*)d_in[1];
  const float* grid   = (const float*)d_in[2];
  const float* atoms  = (const float*)d_in[3];
  (void)in_sizes; (void)n_in; (void)out_size;

  const size_t ws_needed = (size_t)3 * NPTS_TOTAL * sizeof(float);
  if (ws_size >= ws_needed) {
    const int gridA = (NPTS_TOTAL + 255) / 256;  // 768 blocks... actually 767*256/256
    hipLaunchKernelGGL(shdict_gather, dim3(gridA), dim3(256), 0, stream,
                       rays_o, rays_d, grid, atoms, (float*)d_out, (float*)d_ws);
    hipLaunchKernelGGL(shdict_scan, dim3(NRAYS/4), dim3(256), 0, stream,
                       rays_o, rays_d, (const float*)d_ws, (float*)d_out);
  } else {
    hipLaunchKernelGGL(shdict_render_fused, dim3(NRAYS), dim3(256), 0, stream,
                       rays_o, rays_d, grid, atoms, (float*)d_out);
  }
}

// Round 4
// 251.388 us; speedup vs baseline: 1.2019x; 1.0976x over previous
//
#include <hip/hip_runtime.h>
#include <math.h>

namespace {
constexpr int COARSE = 32;
constexpr int NATOMS = 16;
constexpr int NPT    = 767;   // N_INT - 1
constexpr int NRAYS  = 256;
constexpr int NPTS_TOTAL = NRAYS * NPT;              // 196352
constexpr int PTS_PER_BLK = 32;                      // 256 threads / 8 lanes per point
constexpr int GATHER_BLOCKS = NPTS_TOTAL / PTS_PER_BLK;  // 6136 (= 8 * 767, exact)
constexpr double VOXEL_D = 1.3 * 2.0 / 32.0 / 4.0;
constexpr float  VOXEL_F = (float)VOXEL_D;
constexpr float  STEP_F  = (float)(VOXEL_D / 2.0);
constexpr float  RAD     = 1.3f;
}

// ---------------------------------------------------------------------------
// Kernel A: corner-parallel gather. 8 lanes per sample point, 1 corner each.
// 256-thread block = 32 points. Partial sums (pre-scaled by trilinear w)
// combine via 3 shfl_xor rounds within the aligned 8-lane group.
// ---------------------------------------------------------------------------
__global__ __launch_bounds__(256)
void shdict_gather(const float* __restrict__ rays_o,
                   const float* __restrict__ rays_d,
                   const float* __restrict__ grid,
                   const float* __restrict__ atoms,
                   float* __restrict__ out,
                   float* __restrict__ ws)
{
  int bid = blockIdx.x;
  // XCD-chunked bijective swizzle: consecutive blocks (consecutive ray
  // segments) stay on one XCD's L2. 6136 % 8 == 0 so this is exact.
  bid = (bid & 7) * (GATHER_BLOCKS / 8) + (bid >> 3);

  const int corner = threadIdx.x & 7;   // this lane's corner
  const int pib    = threadIdx.x >> 3;  // point within block
  const int p      = bid * PTS_PER_BLK + pib;
  const int ray    = p / NPT;
  const int j      = p - ray * NPT;

  const float ox = rays_o[ray*3+0], oy = rays_o[ray*3+1], oz = rays_o[ray*3+2];
  const float dx = rays_d[ray*3+0], dy = rays_d[ray*3+1], dz = rays_d[ray*3+2];

  const float m0 = fminf((RAD - ox)/dx, (-RAD - ox)/dx);
  const float m1 = fminf((RAD - oy)/dy, (-RAD - oy)/dy);
  const float m2 = fminf((RAD - oz)/dz, (-RAD - oz)/dz);
  const float start = fmaxf(fmaxf(m0, m1), m2);
  const float dnorm = sqrtf(dx*dx + dy*dy + dz*dz);

  const float t  = start + (float)j * STEP_F;
  const float px = ox + t*dx;
  const float py = oy + t*dy;
  const float pz = oz + t*dz;
  const bool inb = (px > -RAD) && (px < RAD) && (py > -RAD) && (py < RAD)
                && (pz > -RAD) && (pz < RAD);

  float a = 0.0f, r0 = 0.5f, r1 = 0.5f, r2 = 0.5f;
  if (inb) {
    const float ux = (px + RAD) / VOXEL_F;
    const float uy = (py + RAD) / VOXEL_F;
    const float uz = (pz + RAD) / VOXEL_F;

    const float sx = (corner & 4) ? 0.5f : -0.5f;
    const float sy = (corner & 2) ? 0.5f : -0.5f;
    const float sz = (corner & 1) ? 0.5f : -0.5f;
    const float pfx = fminf(fmaxf(floorf(ux + sx), 0.0f), 127.0f);
    const float pfy = fminf(fmaxf(floorf(uy + sy), 0.0f), 127.0f);
    const float pfz = fminf(fmaxf(floorf(uz + sz), 0.0f), 127.0f);
    const float fx = fabsf(ux - (pfx + 0.5f));
    const float fy = fabsf(uy - (pfy + 0.5f));
    const float fz = fabsf(uz - (pfz + 0.5f));
    const float w = (1.0f-fx)*(1.0f-fy)*(1.0f-fz);
    const int ix = (int)pfx, iy = (int)pfy, iz = (int)pfz;
    const int cell = ((ix >> 2)*COARSE + (iy >> 2))*COARSE + (iz >> 2);
    const int fine = ((ix & 3)*4 + (iy & 3))*4 + (iz & 3);
    const float4* cv = (const float4*)(grid + (long)cell*448);
    const float4* fv = (const float4*)(atoms + (long)fine*448);

    float4 res[7];
    #pragma unroll
    for (int q = 0; q < 7; ++q) res[q] = make_float4(0.f,0.f,0.f,0.f);
    for (int aa = 0; aa < NATOMS; ++aa) {
      #pragma unroll
      for (int q = 0; q < 7; ++q) {
        const float4 c = cv[aa*7 + q];
        const float4 f = fv[aa*7 + q];
        res[q].x += c.x*f.x;
        res[q].y += c.y*f.y;
        res[q].z += c.z*f.z;
        res[q].w += c.w*f.w;
      }
    }
    #pragma unroll
    for (int q = 0; q < 7; ++q) {
      res[q].x *= w; res[q].y *= w; res[q].z *= w; res[q].w *= w;
    }

    // Sum the 8 corners across the aligned 8-lane group. All 8 lanes of a
    // point share the same exec state (inb is per-point), so partners are
    // always active.
    #pragma unroll
    for (int off = 1; off <= 4; off <<= 1) {
      #pragma unroll
      for (int q = 0; q < 7; ++q) {
        res[q].x += __shfl_xor(res[q].x, off, 64);
        res[q].y += __shfl_xor(res[q].y, off, 64);
        res[q].z += __shfl_xor(res[q].z, off, 64);
        res[q].w += __shfl_xor(res[q].w, off, 64);
      }
    }

    const float* data = (const float*)res;
    const float sigma = fmaxf(data[27], 0.0f);
    a = 1.0f - expf(-sigma * (STEP_F * dnorm));

    const float inx = dx/dnorm, iny = dy/dnorm, inz = dz/dnorm;
    float sh[9];
    sh[0] = 0.28209479177387814f;
    sh[1] = -0.4886025119029199f*iny;
    sh[2] =  0.4886025119029199f*inz;
    sh[3] = -0.4886025119029199f*inx;
    sh[4] =  1.0925484305920792f*inx*iny;
    sh[5] = -1.0925484305920792f*iny*inz;
    sh[6] =  0.31539156525252005f*(2.0f*inz*inz - inx*inx - iny*iny);
    sh[7] = -1.0925484305920792f*inx*inz;
    sh[8] =  0.5462742152960396f*(inx*inx - iny*iny);

    float p0 = 0.f, p1 = 0.f, p2 = 0.f;
    #pragma unroll
    for (int k = 0; k < 9; ++k) {
      p0 += sh[k]*data[k];
      p1 += sh[k]*data[9+k];
      p2 += sh[k]*data[18+k];
    }
    r0 = 1.0f/(1.0f + expf(-p0));
    r1 = 1.0f/(1.0f + expf(-p1));
    r2 = 1.0f/(1.0f + expf(-p2));
  }

  if (corner == 0) {
    out[NRAYS*3 + p] = a;           // alpha output plane
    ws[0*NPTS_TOTAL + p] = r0;
    ws[1*NPTS_TOTAL + p] = r1;
    ws[2*NPTS_TOTAL + p] = r2;
  }
}

// ---------------------------------------------------------------------------
// Kernel B: transmittance scan + reductions. One wave per ray.
// ---------------------------------------------------------------------------
__global__ __launch_bounds__(256)
void shdict_scan(const float* __restrict__ rays_o,
                 const float* __restrict__ rays_d,
                 const float* __restrict__ ws,
                 float* __restrict__ out)
{
  const int wave = threadIdx.x >> 6;
  const int lane = threadIdx.x & 63;
  const int ray  = blockIdx.x * 4 + wave;
  if (ray >= NRAYS) return;

  const float ox = rays_o[ray*3+0], oy = rays_o[ray*3+1], oz = rays_o[ray*3+2];
  const float dx = rays_d[ray*3+0], dy = rays_d[ray*3+1], dz = rays_d[ray*3+2];
  const float m0 = fminf((RAD - ox)/dx, (-RAD - ox)/dx);
  const float m1 = fminf((RAD - oy)/dy, (-RAD - oy)/dy);
  const float m2 = fminf((RAD - oz)/dz, (-RAD - oz)/dz);
  const float start = fmaxf(fmaxf(m0, m1), m2);

  const float* alpha = out + NRAYS*3 + ray*NPT;

  float carry = 1.0f;
  float acc = 0.f, dep = 0.f, c0 = 0.f, c1 = 0.f, c2 = 0.f;
  for (int chunk = 0; chunk < 12; ++chunk) {
    const int j = chunk*64 + lane;
    const float a = (j < NPT) ? alpha[j] : 0.0f;
    const float v = 1.0f - a + 1e-10f;
    float s = v;
    #pragma unroll
    for (int off = 1; off < 64; off <<= 1) {
      const float o = __shfl_up(s, off, 64);
      if (lane >= off) s *= o;
    }
    float excl = __shfl_up(s, 1, 64);
    if (lane == 0) excl = 1.0f;
    const float T = carry * excl;
    if (j < NPT) {
      const int p = ray*NPT + j;
      const float al = a * T;
      acc += al;
      const float t = start + (float)j * STEP_F;
      dep += al * t;
      c0 += al * ws[0*NPTS_TOTAL + p];
      c1 += al * ws[1*NPTS_TOTAL + p];
      c2 += al * ws[2*NPTS_TOTAL + p];
    }
    carry *= __shfl(s, 63, 64);
  }
  #pragma unroll
  for (int off = 32; off >= 1; off >>= 1) {
    acc += __shfl_down(acc, off, 64);
    dep += __shfl_down(dep, off, 64);
    c0  += __shfl_down(c0,  off, 64);
    c1  += __shfl_down(c1,  off, 64);
    c2  += __shfl_down(c2,  off, 64);
  }
  if (lane == 0) {
    const float bg = 1.0f - acc;
    out[ray*3+0] = c0 + bg;
    out[ray*3+1] = c1 + bg;
    out[ray*3+2] = c2 + bg;
    out[NRAYS*3 + NRAYS*NPT + ray] = dep;
    if (ray == 0) out[NRAYS*3 + NRAYS*NPT + NRAYS] = 0.0f;
  }
}

// ---------------------------------------------------------------------------
// Fallback: fused single-kernel version (used only if ws is too small).
// ---------------------------------------------------------------------------
__global__ __launch_bounds__(256)
void shdict_render_fused(const float* __restrict__ rays_o,
                         const float* __restrict__ rays_d,
                         const float* __restrict__ grid,
                         const float* __restrict__ atoms,
                         float* __restrict__ out)
{
  const int ray = blockIdx.x;
  const int tid = threadIdx.x;

  __shared__ float s_alpha[NPT];
  __shared__ float s_rgb[NPT][3];

  const float ox = rays_o[ray*3+0], oy = rays_o[ray*3+1], oz = rays_o[ray*3+2];
  const float dx = rays_d[ray*3+0], dy = rays_d[ray*3+1], dz = rays_d[ray*3+2];

  const float m0 = fminf((RAD - ox)/dx, (-RAD - ox)/dx);
  const float m1 = fminf((RAD - oy)/dy, (-RAD - oy)/dy);
  const float m2 = fminf((RAD - oz)/dz, (-RAD - oz)/dz);
  const float start = fmaxf(fmaxf(m0, m1), m2);

  const float dnorm = sqrtf(dx*dx + dy*dy + dz*dz);
  const float inx = dx/dnorm, iny = dy/dnorm, inz = dz/dnorm;
  float sh[9];
  sh[0] = 0.28209479177387814f;
  sh[1] = -0.4886025119029199f*iny;
  sh[2] =  0.4886025119029199f*inz;
  sh[3] = -0.4886025119029199f*inx;
  sh[4] =  1.0925484305920792f*inx*iny;
  sh[5] = -1.0925484305920792f*iny*inz;
  sh[6] =  0.31539156525252005f*(2.0f*inz*inz - inx*inx - iny*iny);
  sh[7] = -1.0925484305920792f*inx*inz;
  sh[8] =  0.5462742152960396f*(inx*inx - iny*iny);

  float* alpha_out = out + NRAYS*3;

  for (int j = tid; j < NPT; j += 256) {
    const float t  = start + (float)j * STEP_F;
    const float px = ox + t*dx;
    const float py = oy + t*dy;
    const float pz = oz + t*dz;
    const bool inb = (px > -RAD) && (px < RAD) && (py > -RAD) && (py < RAD)
                  && (pz > -RAD) && (pz < RAD);
    float a = 0.0f, r0 = 0.5f, r1 = 0.5f, r2 = 0.5f;
    if (inb) {
      const float ux = (px + RAD) / VOXEL_F;
      const float uy = (py + RAD) / VOXEL_F;
      const float uz = (pz + RAD) / VOXEL_F;
      float4 acc4[7];
      #pragma unroll
      for (int q = 0; q < 7; ++q) acc4[q] = make_float4(0.f,0.f,0.f,0.f);
      for (int corner = 0; corner < 8; ++corner) {
        const float sx = (corner & 4) ? 0.5f : -0.5f;
        const float sy = (corner & 2) ? 0.5f : -0.5f;
        const float sz = (corner & 1) ? 0.5f : -0.5f;
        const float pfx = fminf(fmaxf(floorf(ux + sx), 0.0f), 127.0f);
        const float pfy = fminf(fmaxf(floorf(uy + sy), 0.0f), 127.0f);
        const float pfz = fminf(fmaxf(floorf(uz + sz), 0.0f), 127.0f);
        const float fx = fabsf(ux - (pfx + 0.5f));
        const float fy = fabsf(uy - (pfy + 0.5f));
        const float fz = fabsf(uz - (pfz + 0.5f));
        const float w = (1.0f-fx)*(1.0f-fy)*(1.0f-fz);
        const int ix = (int)pfx, iy = (int)pfy, iz = (int)pfz;
        const int cell = ((ix >> 2)*COARSE + (iy >> 2))*COARSE + (iz >> 2);
        const int fine = ((ix & 3)*4 + (iy & 3))*4 + (iz & 3);
        const float4* cv = (const float4*)(grid + (long)cell*448);
        const float4* fv = (const float4*)(atoms + (long)fine*448);
        float4 res[7];
        #pragma unroll
        for (int q = 0; q < 7; ++q) res[q] = make_float4(0.f,0.f,0.f,0.f);
        for (int aa = 0; aa < NATOMS; ++aa) {
          #pragma unroll
          for (int q = 0; q < 7; ++q) {
            const float4 c = cv[aa*7 + q];
            const float4 f = fv[aa*7 + q];
            res[q].x += c.x*f.x;
            res[q].y += c.y*f.y;
            res[q].z += c.z*f.z;
            res[q].w += c.w*f.w;
          }
        }
        #pragma unroll
        for (int q = 0; q < 7; ++q) {
          acc4[q].x += w*res[q].x;
          acc4[q].y += w*res[q].y;
          acc4[q].z += w*res[q].z;
          acc4[q].w += w*res[q].w;
        }
      }
      const float* data = (const float*)acc4;
      const float sigma = fmaxf(data[27], 0.0f);
      a = 1.0f - expf(-sigma * (STEP_F * dnorm));
      float p0 = 0.f, p1 = 0.f, p2 = 0.f;
      #pragma unroll
      for (int k = 0; k < 9; ++k) {
        p0 += sh[k]*data[k];
        p1 += sh[k]*data[9+k];
        p2 += sh[k]*data[18+k];
      }
      r0 = 1.0f/(1.0f + expf(-p0));
      r1 = 1.0f/(1.0f + expf(-p1));
      r2 = 1.0f/(1.0f + expf(-p2));
    }
    s_alpha[j]  = a;
    s_rgb[j][0] = r0; s_rgb[j][1] = r1; s_rgb[j][2] = r2;
    alpha_out[ray*NPT + j] = a;
  }
  __syncthreads();

  if (tid < 64) {
    const int lane = tid;
    float carry = 1.0f;
    float acc = 0.f, dep = 0.f, c0 = 0.f, c1 = 0.f, c2 = 0.f;
    for (int chunk = 0; chunk < 12; ++chunk) {
      const int j = chunk*64 + lane;
      const float a = (j < NPT) ? s_alpha[j] : 0.0f;
      const float v = 1.0f - a + 1e-10f;
      float s = v;
      #pragma unroll
      for (int off = 1; off < 64; off <<= 1) {
        const float o = __shfl_up(s, off, 64);
        if (lane >= off) s *= o;
      }
      float excl = __shfl_up(s, 1, 64);
      if (lane == 0) excl = 1.0f;
      const float T = carry * excl;
      if (j < NPT) {
        const float al = a * T;
        acc += al;
        dep += al * (start + (float)j * STEP_F);
        c0 += al * s_rgb[j][0];
        c1 += al * s_rgb[j][1];
        c2 += al * s_rgb[j][2];
      }
      carry *= __shfl(s, 63, 64);
    }
    #pragma unroll
    for (int off = 32; off >= 1; off >>= 1) {
      acc += __shfl_down(acc, off, 64);
      dep += __shfl_down(dep, off, 64);
      c0  += __shfl_down(c0,  off, 64);
      c1  += __shfl_down(c1,  off, 64);
      c2  += __shfl_down(c2,  off, 64);
    }
    if (lane == 0) {
      const float bg = 1.0f - acc;
      out[ray*3+0] = c0 + bg;
      out[ray*3+1] = c1 + bg;
      out[ray*3+2] = c2 + bg;
      out[NRAYS*3 + NRAYS*NPT + ray] = dep;
      if (ray == 0) out[NRAYS*3 + NRAYS*NPT + NRAYS] = 0.0f;
    }
  }
}

extern "C" void kernel_launch(void* const* d_in, const int* in_sizes, int n_in,
                              void* d_out, int out_size, void* d_ws, size_t ws_size,
                              hipStream_t stream) {
  const float* rays_o = (const float*)d_in[0];
  const float* rays_d = (const float*)d_in[1];
  const float* grid   = (const float*)d_in[2];
  const float* atoms  = (const float*)d_in[3];
  (void)in_sizes; (void)n_in; (void)out_size;

  const size_t ws_needed = (size_t)3 * NPTS_TOTAL * sizeof(float);
  if (ws_size >= ws_needed) {
    hipLaunchKernelGGL(shdict_gather, dim3(GATHER_BLOCKS), dim3(256), 0, stream,
                       rays_o, rays_d, grid, atoms, (float*)d_out, (float*)d_ws);
    hipLaunchKernelGGL(shdict_scan, dim3(NRAYS/4), dim3(256), 0, stream,
                       rays_o, rays_d, (const float*)d_ws, (float*)d_out);
  } else {
    hipLaunchKernelGGL(shdict_render_fused, dim3(NRAYS), dim3(256), 0, stream,
                       rays_o, rays_d, grid, atoms, (float*)d_out);
  }
}

// Round 5
// 137.846 us; speedup vs baseline: 2.1918x; 1.8237x over previous
//
#include <hip/hip_runtime.h>
#include <math.h>

namespace {
constexpr int COARSE = 32;
constexpr int NPT    = 767;   // N_INT - 1
constexpr int NRAYS  = 256;
constexpr int NPTS_TOTAL = NRAYS * NPT;          // 196352
constexpr int GATHER_BLOCKS = NPTS_TOTAL / 4;    // 49088: 1 wave per point, 4 waves/block
constexpr double VOXEL_D = 1.3 * 2.0 / 32.0 / 4.0;
constexpr float  VOXEL_F = (float)VOXEL_D;
constexpr float  STEP_F  = (float)(VOXEL_D / 2.0);
constexpr float  RAD     = 1.3f;
}

// ---------------------------------------------------------------------------
// Kernel A: wave-cooperative gather. One 64-lane wave per sample point.
// The wave loads each needed coarse cell / fine cell as CONTIGUOUS float4
// runs (lane, 64+lane) -> minimum cache-line touches per load instruction
// (TA/TD line-serialization is the measured bottleneck of rounds 1-4).
// Elementwise products are accumulated per-lane over corners; the SH/sigma
// projection (linear in the products) is folded per-element in the epilogue
// and reduced with one 6-round butterfly.
// ---------------------------------------------------------------------------
__global__ __launch_bounds__(256)
void shdict_gather(const float* __restrict__ rays_o,
                   const float* __restrict__ rays_d,
                   const float* __restrict__ grid,
                   const float* __restrict__ atoms,
                   float* __restrict__ out,
                   float* __restrict__ ws)
{
  int bid = blockIdx.x;
  // XCD-chunked bijective swizzle (49088 % 8 == 0): keeps consecutive ray
  // segments (which share cells) on one XCD's L2.
  bid = (bid & 7) * (GATHER_BLOCKS / 8) + (bid >> 3);

  const int lane = threadIdx.x & 63;
  const int wv   = threadIdx.x >> 6;
  const int p    = bid * 4 + wv;         // this wave's sample point
  const int ray  = p / NPT;
  const int j    = p - ray * NPT;

  __shared__ float sh_lds[4][9];         // per-wave SH basis table

  const float ox = rays_o[ray*3+0], oy = rays_o[ray*3+1], oz = rays_o[ray*3+2];
  const float dx = rays_d[ray*3+0], dy = rays_d[ray*3+1], dz = rays_d[ray*3+2];

  const float m0 = fminf((RAD - ox)/dx, (-RAD - ox)/dx);
  const float m1 = fminf((RAD - oy)/dy, (-RAD - oy)/dy);
  const float m2 = fminf((RAD - oz)/dz, (-RAD - oz)/dz);
  const float start = fmaxf(fmaxf(m0, m1), m2);
  const float dnorm = sqrtf(dx*dx + dy*dy + dz*dz);

  const float t  = start + (float)j * STEP_F;
  const float px = ox + t*dx;
  const float py = oy + t*dy;
  const float pz = oz + t*dz;
  const bool inb = (px > -RAD) && (px < RAD) && (py > -RAD) && (py < RAD)
                && (pz > -RAD) && (pz < RAD);   // wave-uniform

  float a = 0.0f, r0 = 0.5f, r1 = 0.5f, r2 = 0.5f;

  if (inb) {
    // --- SH basis table (per-wave; lane 0 writes, in-wave DS ordering) ---
    const float inx = dx/dnorm, iny = dy/dnorm, inz = dz/dnorm;
    const float sh0 = 0.28209479177387814f;
    const float sh1 = -0.4886025119029199f*iny;
    const float sh2 =  0.4886025119029199f*inz;
    const float sh3 = -0.4886025119029199f*inx;
    const float sh4 =  1.0925484305920792f*inx*iny;
    const float sh5 = -1.0925484305920792f*iny*inz;
    const float sh6 =  0.31539156525252005f*(2.0f*inz*inz - inx*inx - iny*iny);
    const float sh7 = -1.0925484305920792f*inx*inz;
    const float sh8 =  0.5462742152960396f*(inx*inx - iny*iny);
    if (lane == 0) {
      sh_lds[wv][0] = sh0; sh_lds[wv][1] = sh1; sh_lds[wv][2] = sh2;
      sh_lds[wv][3] = sh3; sh_lds[wv][4] = sh4; sh_lds[wv][5] = sh5;
      sh_lds[wv][6] = sh6; sh_lds[wv][7] = sh7; sh_lds[wv][8] = sh8;
    }

    const float ux = (px + RAD) / VOXEL_F;
    const float uy = (py + RAD) / VOXEL_F;
    const float uz = (pz + RAD) / VOXEL_F;

    const float4* gp = (const float4*)grid;
    const float4* ap = (const float4*)atoms;

    float4 acc1 = make_float4(0.f,0.f,0.f,0.f);
    float4 acc2 = make_float4(0.f,0.f,0.f,0.f);
    float4 c1 = make_float4(0.f,0.f,0.f,0.f);
    float4 c2 = make_float4(0.f,0.f,0.f,0.f);
    int pcell = -1;

    // Gray-code corner order: consecutive corners differ in one axis ->
    // maximizes consecutive same-coarse-cell hits for the dedup branch.
    constexpr int co[8] = {0,1,3,2,6,7,5,4};
    #pragma unroll
    for (int ci = 0; ci < 8; ++ci) {
      const int corner = co[ci];
      const float sx = (corner & 4) ? 0.5f : -0.5f;
      const float sy = (corner & 2) ? 0.5f : -0.5f;
      const float sz = (corner & 1) ? 0.5f : -0.5f;
      const float pfx = fminf(fmaxf(floorf(ux + sx), 0.0f), 127.0f);
      const float pfy = fminf(fmaxf(floorf(uy + sy), 0.0f), 127.0f);
      const float pfz = fminf(fmaxf(floorf(uz + sz), 0.0f), 127.0f);
      const float fx = fabsf(ux - (pfx + 0.5f));
      const float fy = fabsf(uy - (pfy + 0.5f));
      const float fz = fabsf(uz - (pfz + 0.5f));
      const float w = (1.0f-fx)*(1.0f-fy)*(1.0f-fz);
      const int ix = (int)pfx, iy = (int)pfy, iz = (int)pfz;
      const int cell = ((ix >> 2)*COARSE + (iy >> 2))*COARSE + (iz >> 2);
      const int fine = ((ix & 3)*4 + (iy & 3))*4 + (iz & 3);

      if (cell != pcell) {                       // wave-uniform branch
        const float4* cv = gp + (size_t)cell * 112;
        c1 = cv[lane];
        if (lane < 48) c2 = cv[64 + lane];
        pcell = cell;
      }
      const float4* fv = ap + (size_t)fine * 112;
      const float4 f1 = fv[lane];
      acc1.x += w * c1.x * f1.x;
      acc1.y += w * c1.y * f1.y;
      acc1.z += w * c1.z * f1.z;
      acc1.w += w * c1.w * f1.w;
      if (lane < 48) {
        const float4 f2 = fv[64 + lane];
        acc2.x += w * c2.x * f2.x;
        acc2.y += w * c2.y * f2.y;
        acc2.z += w * c2.z * f2.z;
        acc2.w += w * c2.w * f2.w;
      }
    }

    // --- epilogue: fold SH coefficients per element, butterfly-reduce ---
    // element e -> (atom a = e/28, d = e%28); d<27 feeds p[d/9] with sh[d%9],
    // d==27 feeds sigma. Lanes >=48 have acc2 == 0, contributions vanish.
    const float accs[8] = {acc1.x, acc1.y, acc1.z, acc1.w,
                           acc2.x, acc2.y, acc2.z, acc2.w};
    float p0 = 0.f, p1 = 0.f, p2 = 0.f, s = 0.f;
    #pragma unroll
    for (int ii = 0; ii < 8; ++ii) {
      const int e = (ii < 4) ? (4*lane + ii) : (256 + 4*lane + (ii - 4));
      const int d = e % 28;
      const float shv = sh_lds[wv][d % 9];
      const float v = accs[ii];
      p0 += v * ((d < 9) ? shv : 0.f);
      p1 += v * ((d >= 9 && d < 18) ? shv : 0.f);
      p2 += v * ((d >= 18 && d < 27) ? shv : 0.f);
      s  += (d == 27) ? v : 0.f;
    }
    #pragma unroll
    for (int off = 1; off < 64; off <<= 1) {
      p0 += __shfl_xor(p0, off, 64);
      p1 += __shfl_xor(p1, off, 64);
      p2 += __shfl_xor(p2, off, 64);
      s  += __shfl_xor(s,  off, 64);
    }

    const float sigma = fmaxf(s, 0.0f);
    a  = 1.0f - expf(-sigma * (STEP_F * dnorm));
    r0 = 1.0f/(1.0f + expf(-p0));
    r1 = 1.0f/(1.0f + expf(-p1));
    r2 = 1.0f/(1.0f + expf(-p2));
  }

  if (lane == 0) {
    out[NRAYS*3 + p] = a;             // alpha output plane
    ws[0*NPTS_TOTAL + p] = r0;
    ws[1*NPTS_TOTAL + p] = r1;
    ws[2*NPTS_TOTAL + p] = r2;
  }
}

// ---------------------------------------------------------------------------
// Kernel B: transmittance scan + reductions. One wave per ray.
// ---------------------------------------------------------------------------
__global__ __launch_bounds__(256)
void shdict_scan(const float* __restrict__ rays_o,
                 const float* __restrict__ rays_d,
                 const float* __restrict__ ws,
                 float* __restrict__ out)
{
  const int wave = threadIdx.x >> 6;
  const int lane = threadIdx.x & 63;
  const int ray  = blockIdx.x * 4 + wave;
  if (ray >= NRAYS) return;

  const float ox = rays_o[ray*3+0], oy = rays_o[ray*3+1], oz = rays_o[ray*3+2];
  const float dx = rays_d[ray*3+0], dy = rays_d[ray*3+1], dz = rays_d[ray*3+2];
  const float m0 = fminf((RAD - ox)/dx, (-RAD - ox)/dx);
  const float m1 = fminf((RAD - oy)/dy, (-RAD - oy)/dy);
  const float m2 = fminf((RAD - oz)/dz, (-RAD - oz)/dz);
  const float start = fmaxf(fmaxf(m0, m1), m2);

  const float* alpha = out + NRAYS*3 + ray*NPT;

  float carry = 1.0f;
  float acc = 0.f, dep = 0.f, c0 = 0.f, c1 = 0.f, c2 = 0.f;
  for (int chunk = 0; chunk < 12; ++chunk) {
    const int j = chunk*64 + lane;
    const float a = (j < NPT) ? alpha[j] : 0.0f;
    const float v = 1.0f - a + 1e-10f;
    float s = v;
    #pragma unroll
    for (int off = 1; off < 64; off <<= 1) {
      const float o = __shfl_up(s, off, 64);
      if (lane >= off) s *= o;
    }
    float excl = __shfl_up(s, 1, 64);
    if (lane == 0) excl = 1.0f;
    const float T = carry * excl;
    if (j < NPT) {
      const int p = ray*NPT + j;
      const float al = a * T;
      acc += al;
      const float t = start + (float)j * STEP_F;
      dep += al * t;
      c0 += al * ws[0*NPTS_TOTAL + p];
      c1 += al * ws[1*NPTS_TOTAL + p];
      c2 += al * ws[2*NPTS_TOTAL + p];
    }
    carry *= __shfl(s, 63, 64);
  }
  #pragma unroll
  for (int off = 32; off >= 1; off >>= 1) {
    acc += __shfl_down(acc, off, 64);
    dep += __shfl_down(dep, off, 64);
    c0  += __shfl_down(c0,  off, 64);
    c1  += __shfl_down(c1,  off, 64);
    c2  += __shfl_down(c2,  off, 64);
  }
  if (lane == 0) {
    const float bg = 1.0f - acc;
    out[ray*3+0] = c0 + bg;
    out[ray*3+1] = c1 + bg;
    out[ray*3+2] = c2 + bg;
    out[NRAYS*3 + NRAYS*NPT + ray] = dep;
    if (ray == 0) out[NRAYS*3 + NRAYS*NPT + NRAYS] = 0.0f;
  }
}

// ---------------------------------------------------------------------------
// Fallback: fused single-kernel version (used only if ws is too small).
// ---------------------------------------------------------------------------
__global__ __launch_bounds__(256)
void shdict_render_fused(const float* __restrict__ rays_o,
                         const float* __restrict__ rays_d,
                         const float* __restrict__ grid,
                         const float* __restrict__ atoms,
                         float* __restrict__ out)
{
  const int ray = blockIdx.x;
  const int tid = threadIdx.x;

  __shared__ float s_alpha[NPT];
  __shared__ float s_rgb[NPT][3];

  const float ox = rays_o[ray*3+0], oy = rays_o[ray*3+1], oz = rays_o[ray*3+2];
  const float dx = rays_d[ray*3+0], dy = rays_d[ray*3+1], dz = rays_d[ray*3+2];

  const float m0 = fminf((RAD - ox)/dx, (-RAD - ox)/dx);
  const float m1 = fminf((RAD - oy)/dy, (-RAD - oy)/dy);
  const float m2 = fminf((RAD - oz)/dz, (-RAD - oz)/dz);
  const float start = fmaxf(fmaxf(m0, m1), m2);

  const float dnorm = sqrtf(dx*dx + dy*dy + dz*dz);
  const float inx = dx/dnorm, iny = dy/dnorm, inz = dz/dnorm;
  float sh[9];
  sh[0] = 0.28209479177387814f;
  sh[1] = -0.4886025119029199f*iny;
  sh[2] =  0.4886025119029199f*inz;
  sh[3] = -0.4886025119029199f*inx;
  sh[4] =  1.0925484305920792f*inx*iny;
  sh[5] = -1.0925484305920792f*iny*inz;
  sh[6] =  0.31539156525252005f*(2.0f*inz*inz - inx*inx - iny*iny);
  sh[7] = -1.0925484305920792f*inx*inz;
  sh[8] =  0.5462742152960396f*(inx*inx - iny*iny);

  float* alpha_out = out + NRAYS*3;

  for (int j = tid; j < NPT; j += 256) {
    const float t  = start + (float)j * STEP_F;
    const float px = ox + t*dx;
    const float py = oy + t*dy;
    const float pz = oz + t*dz;
    const bool inb = (px > -RAD) && (px < RAD) && (py > -RAD) && (py < RAD)
                  && (pz > -RAD) && (pz < RAD);
    float a = 0.0f, r0 = 0.5f, r1 = 0.5f, r2 = 0.5f;
    if (inb) {
      const float ux = (px + RAD) / VOXEL_F;
      const float uy = (py + RAD) / VOXEL_F;
      const float uz = (pz + RAD) / VOXEL_F;
      float4 acc4[7];
      #pragma unroll
      for (int q = 0; q < 7; ++q) acc4[q] = make_float4(0.f,0.f,0.f,0.f);
      for (int corner = 0; corner < 8; ++corner) {
        const float sx = (corner & 4) ? 0.5f : -0.5f;
        const float sy = (corner & 2) ? 0.5f : -0.5f;
        const float sz = (corner & 1) ? 0.5f : -0.5f;
        const float pfx = fminf(fmaxf(floorf(ux + sx), 0.0f), 127.0f);
        const float pfy = fminf(fmaxf(floorf(uy + sy), 0.0f), 127.0f);
        const float pfz = fminf(fmaxf(floorf(uz + sz), 0.0f), 127.0f);
        const float fx = fabsf(ux - (pfx + 0.5f));
        const float fy = fabsf(uy - (pfy + 0.5f));
        const float fz = fabsf(uz - (pfz + 0.5f));
        const float w = (1.0f-fx)*(1.0f-fy)*(1.0f-fz);
        const int ix = (int)pfx, iy = (int)pfy, iz = (int)pfz;
        const int cell = ((ix >> 2)*COARSE + (iy >> 2))*COARSE + (iz >> 2);
        const int fine = ((ix & 3)*4 + (iy & 3))*4 + (iz & 3);
        const float4* cv = (const float4*)(grid + (long)cell*448);
        const float4* fv = (const float4*)(atoms + (long)fine*448);
        float4 res[7];
        #pragma unroll
        for (int q = 0; q < 7; ++q) res[q] = make_float4(0.f,0.f,0.f,0.f);
        for (int aa = 0; aa < 16; ++aa) {
          #pragma unroll
          for (int q = 0; q < 7; ++q) {
            const float4 c = cv[aa*7 + q];
            const float4 f = fv[aa*7 + q];
            res[q].x += c.x*f.x;
            res[q].y += c.y*f.y;
            res[q].z += c.z*f.z;
            res[q].w += c.w*f.w;
          }
        }
        #pragma unroll
        for (int q = 0; q < 7; ++q) {
          acc4[q].x += w*res[q].x;
          acc4[q].y += w*res[q].y;
          acc4[q].z += w*res[q].z;
          acc4[q].w += w*res[q].w;
        }
      }
      const float* data = (const float*)acc4;
      const float sigma = fmaxf(data[27], 0.0f);
      a = 1.0f - expf(-sigma * (STEP_F * dnorm));
      float p0 = 0.f, p1 = 0.f, p2 = 0.f;
      #pragma unroll
      for (int k = 0; k < 9; ++k) {
        p0 += sh[k]*data[k];
        p1 += sh[k]*data[9+k];
        p2 += sh[k]*data[18+k];
      }
      r0 = 1.0f/(1.0f + expf(-p0));
      r1 = 1.0f/(1.0f + expf(-p1));
      r2 = 1.0f/(1.0f + expf(-p2));
    }
    s_alpha[j]  = a;
    s_rgb[j][0] = r0; s_rgb[j][1] = r1; s_rgb[j][2] = r2;
    alpha_out[ray*NPT + j] = a;
  }
  __syncthreads();

  if (tid < 64) {
    const int lane = tid;
    float carry = 1.0f;
    float acc = 0.f, dep = 0.f, c0 = 0.f, c1 = 0.f, c2 = 0.f;
    for (int chunk = 0; chunk < 12; ++chunk) {
      const int j = chunk*64 + lane;
      const float a = (j < NPT) ? s_alpha[j] : 0.0f;
      const float v = 1.0f - a + 1e-10f;
      float s = v;
      #pragma unroll
      for (int off = 1; off < 64; off <<= 1) {
        const float o = __shfl_up(s, off, 64);
        if (lane >= off) s *= o;
      }
      float excl = __shfl_up(s, 1, 64);
      if (lane == 0) excl = 1.0f;
      const float T = carry * excl;
      if (j < NPT) {
        const float al = a * T;
        acc += al;
        dep += al * (start + (float)j * STEP_F);
        c0 += al * s_rgb[j][0];
        c1 += al * s_rgb[j][1];
        c2 += al * s_rgb[j][2];
      }
      carry *= __shfl(s, 63, 64);
    }
    #pragma unroll
    for (int off = 32; off >= 1; off >>= 1) {
      acc += __shfl_down(acc, off, 64);
      dep += __shfl_down(dep, off, 64);
      c0  += __shfl_down(c0,  off, 64);
      c1  += __shfl_down(c1,  off, 64);
      c2  += __shfl_down(c2,  off, 64);
    }
    if (lane == 0) {
      const float bg = 1.0f - acc;
      out[ray*3+0] = c0 + bg;
      out[ray*3+1] = c1 + bg;
      out[ray*3+2] = c2 + bg;
      out[NRAYS*3 + NRAYS*NPT + ray] = dep;
      if (ray == 0) out[NRAYS*3 + NRAYS*NPT + NRAYS] = 0.0f;
    }
  }
}

extern "C" void kernel_launch(void* const* d_in, const int* in_sizes, int n_in,
                              void* d_out, int out_size, void* d_ws, size_t ws_size,
                              hipStream_t stream) {
  const float* rays_o = (const float*)d_in[0];
  const float* rays_d = (const float*)d_in[1];
  const float* grid   = (const float*)d_in[2];
  const float* atoms  = (const float*)d_in[3];
  (void)in_sizes; (void)n_in; (void)out_size;

  const size_t ws_needed = (size_t)3 * NPTS_TOTAL * sizeof(float);
  if (ws_size >= ws_needed) {
    hipLaunchKernelGGL(shdict_gather, dim3(GATHER_BLOCKS), dim3(256), 0, stream,
                       rays_o, rays_d, grid, atoms, (float*)d_out, (float*)d_ws);
    hipLaunchKernelGGL(shdict_scan, dim3(NRAYS/4), dim3(256), 0, stream,
                       rays_o, rays_d, (const float*)d_ws, (float*)d_out);
  } else {
    hipLaunchKernelGGL(shdict_render_fused, dim3(NRAYS), dim3(256), 0, stream,
                       rays_o, rays_d, grid, atoms, (float*)d_out);
  }
}